// Round 5
// baseline (116.596 us; speedup 1.0000x reference)
//
#include <hip/hip_runtime.h>

#define NQ     12
#define DIM    4096
#define QDEPTH 8
#define T      1024            // 16 waves, 4 per SIMD

// bijective bank swizzle: fold upper nibbles into the low nibble.
// For every pass's access pattern this yields exactly 4 lanes per bank-pair
// (the minimum for 64 lanes x 8B on 32 banks).
__device__ __forceinline__ int SW(int i) {
    return i ^ (((i >> 4) ^ (i >> 8)) & 0xF);
}

template <int CTRL>
__device__ __forceinline__ float dpp_mov(float x) {
    return __int_as_float(__builtin_amdgcn_update_dpp(
        __float_as_int(x), __float_as_int(x), CTRL, 0xF, 0xF, false));
}

// quad-lane gate via DPP (VALU pipe, no LDS): new = X*own + Y*partner,
// C = (Xr,Xi,Yr,Yi) chosen per lane side.
template <int CTRL>
__device__ __forceinline__ void dpp_gate(float2 amp[4], const float4 C) {
#pragma unroll
    for (int c = 0; c < 4; ++c) {
        const float pr = dpp_mov<CTRL>(amp[c].x);
        const float pi = dpp_mov<CTRL>(amp[c].y);
        const float ar = amp[c].x, ai = amp[c].y;
        amp[c].x = C.x * ar - C.y * ai + C.z * pr - C.w * pi;
        amp[c].y = C.x * ai + C.y * ar + C.z * pi + C.w * pr;
    }
}

// in-register gate on amp-index bit m: V0=(m00|m01), V1=(m11|m10)
__device__ __forceinline__ void reg_gate4(float2 amp[4], const int m,
                                          const float4 V0, const float4 V1) {
#pragma unroll
    for (int c = 0; c < 4; ++c) {
        if (c & m) continue;
        const int c1 = c | m;
        const float a0r = amp[c].x,  a0i = amp[c].y;
        const float a1r = amp[c1].x, a1i = amp[c1].y;
        amp[c].x  = V0.x * a0r - V0.y * a0i + V0.z * a1r - V0.w * a1i;
        amp[c].y  = V0.x * a0i + V0.y * a0r + V0.z * a1i + V0.w * a1r;
        amp[c1].x = V1.z * a0r - V1.w * a0i + V1.x * a1r - V1.y * a1i;
        amp[c1].y = V1.z * a0i + V1.w * a0r + V1.x * a1i + V1.y * a1r;
    }
}

// pass g covers wires 4g..4g+3 (i-bits 11-4g..8-4g): c -> high 2 bits of the
// group, tid&3 -> low 2 bits (quad lanes), tid>>2 -> the remaining 8 bits.
__device__ __forceinline__ void addrs(const int g, const int tid,
                                      int ja[4], int ii[4]) {
    const int t2 = tid >> 2, q = tid & 3;
#pragma unroll
    for (int c = 0; c < 4; ++c) {
        int i;
        if (g == 0)      i = (c << 10) | (q << 8) | t2;
        else if (g == 1) i = ((t2 & 0xF0) << 4) | (c << 6) | (q << 4) | (t2 & 0xF);
        else             i = (t2 << 4) | (c << 2) | q;
        ii[c] = i;
        ja[c] = SW(i);
    }
}

__global__ __launch_bounds__(T) void qnn_sim(const float* __restrict__ qw,
                                             const float* __restrict__ w_up,
                                             const float* __restrict__ b_up,
                                             float* __restrict__ row) {
    __shared__ float2 st[DIM];
    __shared__ float4 mats2[96 * 2];   // [wire: m00|m01][wire: m11|m10]
    __shared__ float  zred[T / 64][NQ];
    __shared__ float  zfin[NQ];

    const int tid = threadIdx.x;

    if (tid < 96) {
        const float phi = qw[tid * 3 + 0], theta = qw[tid * 3 + 1], omega = qw[tid * 3 + 2];
        float c, s, sp, cp, sm, cm;
        sincosf(0.5f * theta, &s, &c);
        sincosf(0.5f * (phi + omega), &sp, &cp);
        sincosf(0.5f * (phi - omega), &sm, &cm);
        mats2[tid * 2 + 0] = make_float4(cp * c, -sp * c, -cm * s, -sm * s); // m00|m01
        mats2[tid * 2 + 1] = make_float4(cp * c,  sp * c,  cm * s, -sm * s); // m11|m10
    }
    __syncthreads();

    float2 amp[4];
    int ja[4], ii[4];

#pragma unroll 1
    for (int l = 0; l < QDEPTH; ++l) {
#pragma unroll 1
        for (int g = 0; g < 3; ++g) {
            const bool first = (l == 0 && g == 0);
            const bool last  = (l == QDEPTH - 1 && g == 2);
            addrs(g, tid, ja, ii);
            if (first) {
#pragma unroll
                for (int c = 0; c < 4; ++c)
                    amp[c] = make_float2(ii[c] == 0 ? 1.f : 0.f, 0.f);
            } else {
                __syncthreads();
#pragma unroll
                for (int c = 0; c < 4; ++c) amp[c] = st[ja[c]];
            }
            const float4* G = &mats2[(l * NQ + 4 * g) * 2];
            reg_gate4(amp, 2, G[0], G[1]);                 // wire 4g
            reg_gate4(amp, 1, G[2], G[3]);                 // wire 4g+1
            dpp_gate<0x4E>(amp, G[4 + ((tid >> 1) & 1)]);  // wire 4g+2 (xor lane 2)
            dpp_gate<0xB1>(amp, G[6 + (tid & 1)]);         // wire 4g+3 (xor lane 1)
            if (g == 2 && l < QDEPTH - 1) {
                const int r = l + 1;   // CZ range; layer-7 diag dropped (|amp|^2)
#pragma unroll
                for (int c = 0; c < 4; ++c) {
                    const unsigned i  = (unsigned)ii[c];
                    const unsigned ro = ((i << r) | (i >> (12 - r))) & 0xFFFu;
                    if (__popc(i & ro) & 1) { amp[c].x = -amp[c].x; amp[c].y = -amp[c].y; }
                }
            }
            if (!last) {
#pragma unroll
                for (int c = 0; c < 4; ++c) st[ja[c]] = amp[c];
            }
        }
    }

    // <Z_w>: final amps in regs (last pass g=2, indices ii[c])
    float zp[NQ];
#pragma unroll
    for (int w = 0; w < NQ; ++w) zp[w] = 0.0f;
#pragma unroll
    for (int c = 0; c < 4; ++c) {
        const float pr = amp[c].x * amp[c].x + amp[c].y * amp[c].y;
        const int i = ii[c];
#pragma unroll
        for (int w = 0; w < NQ; ++w) zp[w] += ((i >> (11 - w)) & 1) ? -pr : pr;
    }
#pragma unroll
    for (int w = 0; w < NQ; ++w) {
        float v = zp[w];
        for (int off = 32; off > 0; off >>= 1) v += __shfl_down(v, off, 64);
        zp[w] = v;
    }
    const int wave = tid >> 6, lane = tid & 63;
    if (lane == 0) {
#pragma unroll
        for (int w = 0; w < NQ; ++w) zred[wave][w] = zp[w];
    }
    __syncthreads();
    if (tid < NQ) {
        float v = 0.0f;
#pragma unroll
        for (int k = 0; k < T / 64; ++k) v += zred[k][tid];
        zfin[tid] = v;
    }
    __syncthreads();

    if (tid < 784) {
        float acc = b_up[tid];
#pragma unroll
        for (int j = 0; j < NQ; ++j) acc += zfin[j] * w_up[tid * NQ + j];
        row[tid] = acc;
    }
}

// ---------------------------------------------------------------------------
// Broadcast: 2048 rows x 196 float4. 392 dense blocks; idx%196 is invariant
// across the k-stride because 100352 = 196*512. Fully coalesced stores.
// ---------------------------------------------------------------------------
__global__ __launch_bounds__(256) void qnn_bcast(const float* __restrict__ row,
                                                 float* __restrict__ out) {
    const int idx = blockIdx.x * 256 + threadIdx.x;   // 0..100351
    const float4 v = ((const float4*)row)[idx % 196];
    float4* o = (float4*)out;
#pragma unroll
    for (int k = 0; k < 4; ++k) o[idx + k * 100352] = v;
}

extern "C" void kernel_launch(void* const* d_in, const int* in_sizes, int n_in,
                              void* d_out, int out_size, void* d_ws, size_t ws_size,
                              hipStream_t stream) {
    // inputs: 0:x 1:w_down 2:b_down 3:w_up 4:b_up 5:qweights
    const float* w_up = (const float*)d_in[3];
    const float* b_up = (const float*)d_in[4];
    const float* qw   = (const float*)d_in[5];
    float* row = (float*)d_ws;
    float* out = (float*)d_out;

    qnn_sim<<<1, T, 0, stream>>>(qw, w_up, b_up, row);
    qnn_bcast<<<392, 256, 0, stream>>>(row, out);
}

// Round 6
// 95.743 us; speedup vs baseline: 1.2178x; 1.2178x over previous
//
#include <hip/hip_runtime.h>

#define NQ     12
#define DIM    4096
#define QDEPTH 8
#define T      1024                    // 16 waves, 4 per SIMD
#define STSZ   (DIM + (DIM / 16) * 2)  // R2-proven padding: 2 float2 per 16
#define NBLK   98                      // 98*1024 threads * 4 float4 = 2048*784 floats

__device__ __forceinline__ int AD(int i) { return i + ((i >> 4) << 1); }

template <int CTRL>
__device__ __forceinline__ float dpp_mov(float x) {
    return __int_as_float(__builtin_amdgcn_update_dpp(
        __float_as_int(x), __float_as_int(x), CTRL, 0xF, 0xF, false));
}

// quad-lane gate via DPP (VALU pipe): new = X*own + Y*partner, C=(Xr,Xi,Yr,Yi)
template <int CTRL>
__device__ __forceinline__ void dpp_gate(float2 a[4], const float4 C) {
#pragma unroll
    for (int c = 0; c < 4; ++c) {
        const float pr = dpp_mov<CTRL>(a[c].x);
        const float pi = dpp_mov<CTRL>(a[c].y);
        const float ar = a[c].x, ai = a[c].y;
        a[c].x = C.x * ar - C.y * ai + C.z * pr - C.w * pi;
        a[c].y = C.x * ai + C.y * ar + C.z * pi + C.w * pr;
    }
}

// in-register gate on amp-index bit m: V0=(m00|m01), V1=(m11|m10)
__device__ __forceinline__ void reg_gate(float2 a[4], const int m,
                                         const float4 V0, const float4 V1) {
#pragma unroll
    for (int c = 0; c < 4; ++c) {
        if (c & m) continue;
        const int c1 = c | m;
        const float a0r = a[c].x,  a0i = a[c].y;
        const float a1r = a[c1].x, a1i = a[c1].y;
        a[c].x  = V0.x * a0r - V0.y * a0i + V0.z * a1r - V0.w * a1i;
        a[c].y  = V0.x * a0i + V0.y * a0r + V0.z * a1i + V0.w * a1r;
        a[c1].x = V1.z * a0r - V1.w * a0i + V1.x * a1r - V1.y * a1i;
        a[c1].y = V1.z * a0i + V1.w * a0r + V1.x * a1i + V1.y * a1r;
    }
}

// 4 gates of layer l on wire group g (wires 4g..4g+3)
__device__ __forceinline__ void gates4(float2 a[4], const float4* __restrict__ Gm,
                                       const int tid) {
    reg_gate(a, 2, Gm[0], Gm[1]);                  // wire 4g   (c bit1)
    reg_gate(a, 1, Gm[2], Gm[3]);                  // wire 4g+1 (c bit0)
    dpp_gate<0x4E>(a, Gm[4 + ((tid >> 1) & 1)]);   // wire 4g+2 (quad bit1)
    dpp_gate<0xB1>(a, Gm[6 + (tid & 1)]);          // wire 4g+3 (quad bit0)
}

// one LDS pass: optional load(+barrier), layer-l1 gates, optional CZ(d)+layer-l2
// gates (merged layer boundary), optional store
__device__ __forceinline__ void do_pass(float2* __restrict__ st,
                                        const float4* __restrict__ mats2,
                                        const int ja[4], const int ii[4],
                                        const int g, const int l1, const int d,
                                        const int l2, const bool load,
                                        const bool store, const int tid,
                                        float2 a[4]) {
    if (load) {
        __syncthreads();
#pragma unroll
        for (int c = 0; c < 4; ++c) a[c] = st[ja[c]];
    }
    gates4(a, &mats2[(l1 * NQ + 4 * g) * 2], tid);
    if (d >= 0) {
        const int r = d + 1;   // CZ entangler range for layer d
#pragma unroll
        for (int c = 0; c < 4; ++c) {
            const unsigned i  = (unsigned)ii[c];
            const unsigned ro = ((i << r) | (i >> (12 - r))) & 0xFFFu;
            if (__popc(i & ro) & 1) { a[c].x = -a[c].x; a[c].y = -a[c].y; }
        }
        gates4(a, &mats2[(l2 * NQ + 4 * g) * 2], tid);
    }
    if (store) {
#pragma unroll
        for (int c = 0; c < 4; ++c) st[ja[c]] = a[c];
    }
}

// ---------------------------------------------------------------------------
// Fused kernel: every block redundantly simulates the 12-qubit circuit
// (batch-independent: input encoding is a global phase), computes the single
// output row, and writes its 1/98th of the broadcast output. No inter-block
// communication.
// ---------------------------------------------------------------------------
__global__ __launch_bounds__(T) void qnn_fused(const float* __restrict__ qw,
                                               const float* __restrict__ w_up,
                                               const float* __restrict__ b_up,
                                               float* __restrict__ out) {
    __shared__ float2 st[STSZ];
    __shared__ float4 mats2[96 * 2];   // per wire-gate: [m00|m01][m11|m10]
    __shared__ float  zred[T / 64][NQ];
    __shared__ float  zfin[NQ];
    __shared__ float4 row4[196];       // the 784-float output row

    const int tid = threadIdx.x;

    if (tid < 96) {
        const float phi = qw[tid * 3 + 0], theta = qw[tid * 3 + 1], omega = qw[tid * 3 + 2];
        float c, s, sp, cp, sm, cm;
        sincosf(0.5f * theta, &s, &c);
        sincosf(0.5f * (phi + omega), &sp, &cp);
        sincosf(0.5f * (phi - omega), &sm, &cm);
        // Rot = RZ(omega) RY(theta) RZ(phi)
        mats2[tid * 2 + 0] = make_float4(cp * c, -sp * c, -cm * s, -sm * s); // m00|m01
        mats2[tid * 2 + 1] = make_float4(cp * c,  sp * c,  cm * s, -sm * s); // m11|m10
    }
    __syncthreads();

    // layer-invariant addresses for the three pass layouts (A: bits 11-8,
    // B: bits 7-4, C: bits 3-0 hold the 4-wire group; c=amp idx, q=quad lane)
    const int t2 = tid >> 2, q = tid & 3;
    int jaA[4], iiA[4], jaB[4], iiB[4], jaC[4], iiC[4];
#pragma unroll
    for (int c = 0; c < 4; ++c) {
        iiA[c] = (c << 10) | (q << 8) | t2;
        iiB[c] = ((t2 & 0xF0) << 4) | (c << 6) | (q << 4) | (t2 & 0xF);
        iiC[c] = (t2 << 4) | (c << 2) | q;
        jaA[c] = AD(iiA[c]);
        jaB[c] = AD(iiB[c]);
        jaC[c] = AD(iiC[c]);
    }

    float2 a[4];
    // pass 0 (group A, layer 0): synthesize |0..0> directly, no LDS init needed
#pragma unroll
    for (int c = 0; c < 4; ++c) a[c] = make_float2(iiA[c] == 0 ? 1.f : 0.f, 0.f);
    do_pass(st, mats2, jaA, iiA, 0, 0, -1, -1, false, true,  tid, a);
    // 17-pass merged schedule: group order rotates (ABC CAB BCA ...) so layer
    // boundaries (CZ diag between) fuse into one pass
    do_pass(st, mats2, jaB, iiB, 1, 0, -1, -1, true,  true,  tid, a);
    do_pass(st, mats2, jaC, iiC, 2, 0,  0,  1, true,  true,  tid, a);
    do_pass(st, mats2, jaA, iiA, 0, 1, -1, -1, true,  true,  tid, a);
    do_pass(st, mats2, jaB, iiB, 1, 1,  1,  2, true,  true,  tid, a);
    do_pass(st, mats2, jaC, iiC, 2, 2, -1, -1, true,  true,  tid, a);
    do_pass(st, mats2, jaA, iiA, 0, 2,  2,  3, true,  true,  tid, a);
    do_pass(st, mats2, jaB, iiB, 1, 3, -1, -1, true,  true,  tid, a);
    do_pass(st, mats2, jaC, iiC, 2, 3,  3,  4, true,  true,  tid, a);
    do_pass(st, mats2, jaA, iiA, 0, 4, -1, -1, true,  true,  tid, a);
    do_pass(st, mats2, jaB, iiB, 1, 4,  4,  5, true,  true,  tid, a);
    do_pass(st, mats2, jaC, iiC, 2, 5, -1, -1, true,  true,  tid, a);
    do_pass(st, mats2, jaA, iiA, 0, 5,  5,  6, true,  true,  tid, a);
    do_pass(st, mats2, jaB, iiB, 1, 6, -1, -1, true,  true,  tid, a);
    do_pass(st, mats2, jaC, iiC, 2, 6,  6,  7, true,  true,  tid, a);
    do_pass(st, mats2, jaA, iiA, 0, 7, -1, -1, true,  true,  tid, a);
    // final pass (group B, layer 7): keep amps in registers; layer-7 CZ diag
    // dropped (signs don't change |amp|^2)
    do_pass(st, mats2, jaB, iiB, 1, 7, -1, -1, true,  false, tid, a);

    // <Z_w> reduction; final amp indices are iiB[c]
    float zp[NQ];
#pragma unroll
    for (int w = 0; w < NQ; ++w) zp[w] = 0.0f;
#pragma unroll
    for (int c = 0; c < 4; ++c) {
        const float pr = a[c].x * a[c].x + a[c].y * a[c].y;
        const int i = iiB[c];
#pragma unroll
        for (int w = 0; w < NQ; ++w) zp[w] += ((i >> (11 - w)) & 1) ? -pr : pr;
    }
#pragma unroll
    for (int w = 0; w < NQ; ++w) {
        float v = zp[w];
        for (int off = 32; off > 0; off >>= 1) v += __shfl_down(v, off, 64);
        zp[w] = v;
    }
    const int wave = tid >> 6, lane = tid & 63;
    if (lane == 0) {
#pragma unroll
        for (int w = 0; w < NQ; ++w) zred[wave][w] = zp[w];
    }
    __syncthreads();
    if (tid < NQ) {
        float v = 0.0f;
#pragma unroll
        for (int k = 0; k < T / 64; ++k) v += zred[k][tid];
        zfin[tid] = v;
    }
    __syncthreads();

    // row[i] = b_up[i] + sum_j z[j] * w_up[i,j]
    if (tid < 784) {
        float acc = b_up[tid];
#pragma unroll
        for (int j = 0; j < NQ; ++j) acc += zfin[j] * w_up[tid * NQ + j];
        ((float*)row4)[tid] = acc;
    }
    __syncthreads();

    // broadcast: this block's 1024 float4 slots, k-strided (100352 = 196*512,
    // so idx%196 is invariant across k)
    const int idx = blockIdx.x * T + tid;          // 0..100351
    const float4 v = row4[idx % 196];
    float4* o = (float4*)out;
#pragma unroll
    for (int k = 0; k < 4; ++k) o[idx + k * 100352] = v;
}

extern "C" void kernel_launch(void* const* d_in, const int* in_sizes, int n_in,
                              void* d_out, int out_size, void* d_ws, size_t ws_size,
                              hipStream_t stream) {
    // inputs: 0:x 1:w_down 2:b_down 3:w_up 4:b_up 5:qweights
    const float* w_up = (const float*)d_in[3];
    const float* b_up = (const float*)d_in[4];
    const float* qw   = (const float*)d_in[5];
    float* out = (float*)d_out;

    qnn_fused<<<NBLK, T, 0, stream>>>(qw, w_up, b_up, out);
}

// Round 7
// 93.993 us; speedup vs baseline: 1.2405x; 1.0186x over previous
//
#include <hip/hip_runtime.h>

#define NQ     12
#define DIM    4096
#define QDEPTH 8
#define T      1024                    // 16 waves, 4 per SIMD
#define NBLK   98                      // 98*1024 threads * 4 float4 = 2048*784 floats

// involutive LDS swizzle: fold bits 9-6 into bits 3-0. For both pass layouts
// below this spreads each wave's 64 b64 accesses evenly: 4 lanes/bank-pair
// (the wave64 x 8B floor on 32 banks).
__device__ __forceinline__ int SW(int i) { return i ^ ((i >> 6) & 0xF); }

// wave-internal xor exchanges, all barrier-free:
// KIND 0: xor1 (quad_perm [1,0,3,2])  1: xor2 (quad_perm [2,3,0,1])
// KIND 2: xor4 (ds_swizzle BitMode)   3: xor8 (row_ror:8 == xor8 in row of 16)
template <int KIND>
__device__ __forceinline__ float xlane(float x) {
    if constexpr (KIND == 0)
        return __int_as_float(__builtin_amdgcn_update_dpp(
            __float_as_int(x), __float_as_int(x), 0xB1, 0xF, 0xF, false));
    else if constexpr (KIND == 1)
        return __int_as_float(__builtin_amdgcn_update_dpp(
            __float_as_int(x), __float_as_int(x), 0x4E, 0xF, 0xF, false));
    else if constexpr (KIND == 2)
        return __int_as_float(__builtin_amdgcn_ds_swizzle(
            __float_as_int(x), 0x101F));   // (4<<10)|0x1F: lane ^= 4
    else
        return __int_as_float(__builtin_amdgcn_update_dpp(
            __float_as_int(x), __float_as_int(x), 0x128, 0xF, 0xF, false));
}

// lane-bit gate: new = C.xy*own + C.zw*partner; C=(m00|m01) on side 0,
// (m11|m10) on side 1 (caller selects by lane bit)
template <int KIND>
__device__ __forceinline__ void lane_gate(float2 a[4], const float4 C) {
#pragma unroll
    for (int c = 0; c < 4; ++c) {
        const float pr = xlane<KIND>(a[c].x);
        const float pi = xlane<KIND>(a[c].y);
        const float ar = a[c].x, ai = a[c].y;
        a[c].x = C.x * ar - C.y * ai + C.z * pr - C.w * pi;
        a[c].y = C.x * ai + C.y * ar + C.z * pi + C.w * pr;
    }
}

// in-register gate on amp-index bit m: V0=(m00|m01), V1=(m11|m10)
__device__ __forceinline__ void reg_gate(float2 a[4], const int m,
                                         const float4 V0, const float4 V1) {
#pragma unroll
    for (int c = 0; c < 4; ++c) {
        if (c & m) continue;
        const int c1 = c | m;
        const float a0r = a[c].x,  a0i = a[c].y;
        const float a1r = a[c1].x, a1i = a[c1].y;
        a[c].x  = V0.x * a0r - V0.y * a0i + V0.z * a1r - V0.w * a1i;
        a[c].y  = V0.x * a0i + V0.y * a0r + V0.z * a1i + V0.w * a1r;
        a[c1].x = V1.z * a0r - V1.w * a0i + V1.x * a1r - V1.y * a1i;
        a[c1].y = V1.z * a0i + V1.w * a0r + V1.x * a1i + V1.y * a1r;
    }
}

// 6 gates of layer l on wire group gbase (A: wires 0-5, B: wires 6-11).
// Wire map (state bit for wire w is 11-w): +0 -> c bit1, +1 -> c bit0,
// +2 -> lane bit3 (xor8), +3 -> lane bit2 (xor4), +4 -> lane bit1 (xor2),
// +5 -> lane bit0 (xor1).
__device__ __forceinline__ void gates6(float2 a[4], const float4* __restrict__ m2,
                                       const int gi0, const int lane) {
    const float4* G = m2 + gi0 * 2;
    reg_gate(a, 2, G[0], G[1]);
    reg_gate(a, 1, G[2], G[3]);
    lane_gate<3>(a, G[4  + ((lane >> 3) & 1)]);
    lane_gate<2>(a, G[6  + ((lane >> 2) & 1)]);
    lane_gate<1>(a, G[8  + ((lane >> 1) & 1)]);
    lane_gate<0>(a, G[10 + ( lane       & 1)]);
}

// merged pass: optional barrier+load, layer-l1 group gates, optional
// CZ(d) + layer-l2 group gates, optional store
__device__ __forceinline__ void pass6(float2* __restrict__ st,
                                      const float4* __restrict__ m2,
                                      const int ja[4], const int ii[4],
                                      const int gbase, const int l1, const int d,
                                      const int l2, const bool load,
                                      const bool store, const int lane,
                                      float2 a[4]) {
    if (load) {
        __syncthreads();
#pragma unroll
        for (int c = 0; c < 4; ++c) a[c] = st[ja[c]];
    }
    gates6(a, m2, l1 * NQ + gbase, lane);
    if (d >= 0) {
        const int r = d + 1;   // CZ entangler range for layer d
#pragma unroll
        for (int c = 0; c < 4; ++c) {
            const unsigned i  = (unsigned)ii[c];
            const unsigned ro = ((i << r) | (i >> (12 - r))) & 0xFFFu;
            if (__popc(i & ro) & 1) { a[c].x = -a[c].x; a[c].y = -a[c].y; }
        }
        gates6(a, m2, l2 * NQ + gbase, lane);
    }
    if (store) {
#pragma unroll
        for (int c = 0; c < 4; ++c) st[ja[c]] = a[c];
    }
}

// ---------------------------------------------------------------------------
// Fused kernel: every block redundantly simulates the 12-qubit circuit
// (batch-independent: the RZ input encoding on |0..0> is a global phase),
// computes the single output row, writes its 1/98th of the broadcast output.
// ---------------------------------------------------------------------------
__global__ __launch_bounds__(T) void qnn_fused(const float* __restrict__ qw,
                                               const float* __restrict__ w_up,
                                               const float* __restrict__ b_up,
                                               float* __restrict__ out) {
    __shared__ float2 st[DIM];
    __shared__ float4 mats2[96 * 2];   // per wire-gate: [m00|m01][m11|m10]
    __shared__ float  zred[T / 64][NQ];
    __shared__ float  zfin[NQ];
    __shared__ float4 row4[196];

    const int tid  = threadIdx.x;
    const int lane = tid & 63;

    if (tid < 96) {
        const float phi = qw[tid * 3 + 0], theta = qw[tid * 3 + 1], omega = qw[tid * 3 + 2];
        float c, s, sp, cp, sm, cm;
        sincosf(0.5f * theta, &s, &c);
        sincosf(0.5f * (phi + omega), &sp, &cp);
        sincosf(0.5f * (phi - omega), &sm, &cm);
        // Rot = RZ(omega) RY(theta) RZ(phi)
        mats2[tid * 2 + 0] = make_float4(cp * c, -sp * c, -cm * s, -sm * s); // m00|m01
        mats2[tid * 2 + 1] = make_float4(cp * c,  sp * c,  cm * s, -sm * s); // m11|m10
    }
    __syncthreads();

    // layout A: state bits 11-10 = c, 9-6 = lane bits 3-0, 5-4 = lane bits 5-4,
    //           3-0 = wave id.   (group A wires 0-5 in-thread)
    // layout B: state bits 11-10 = lane bits 5-4, 9-6 = wave id, 5-4 = c,
    //           3-0 = lane bits 3-0.   (group B wires 6-11 in-thread)
    const int w4 = (tid >> 6) & 0xF, l54 = (tid >> 4) & 3, l30 = tid & 0xF;
    int jaA[4], iiA[4], jaB[4], iiB[4];
#pragma unroll
    for (int c = 0; c < 4; ++c) {
        iiA[c] = (c << 10) | (l30 << 6) | (l54 << 4) | w4;
        iiB[c] = (l54 << 10) | (w4 << 6) | (c << 4) | l30;
        jaA[c] = SW(iiA[c]);
        jaB[c] = SW(iiB[c]);
    }

    float2 a[4];
    // P0 (A, layer 0): synthesize |0..0> in registers, store — no LDS init
#pragma unroll
    for (int c = 0; c < 4; ++c) a[c] = make_float2(iiA[c] == 0 ? 1.f : 0.f, 0.f);
    pass6(st, mats2, jaA, iiA, 0, 0, -1, -1, false, true,  lane, a);
    // merged schedule: 9 passes, 8 barriers. CZ(l) sits after all layer-l
    // gates and before all layer-(l+1) gates.
    pass6(st, mats2, jaB, iiB, 6, 0,  0,  1, true,  true,  lane, a);
    pass6(st, mats2, jaA, iiA, 0, 1,  1,  2, true,  true,  lane, a);
    pass6(st, mats2, jaB, iiB, 6, 2,  2,  3, true,  true,  lane, a);
    pass6(st, mats2, jaA, iiA, 0, 3,  3,  4, true,  true,  lane, a);
    pass6(st, mats2, jaB, iiB, 6, 4,  4,  5, true,  true,  lane, a);
    pass6(st, mats2, jaA, iiA, 0, 5,  5,  6, true,  true,  lane, a);
    pass6(st, mats2, jaB, iiB, 6, 6,  6,  7, true,  true,  lane, a);
    // P8 (A, layer 7): layer-7 CZ diag dropped (diagonal before measurement);
    // keep amps in registers for the reduction
    pass6(st, mats2, jaA, iiA, 0, 7, -1, -1, true,  false, lane, a);

    // <Z_w> reduction; final amp indices are iiA[c]
    float zp[NQ];
#pragma unroll
    for (int w = 0; w < NQ; ++w) zp[w] = 0.0f;
#pragma unroll
    for (int c = 0; c < 4; ++c) {
        const float pr = a[c].x * a[c].x + a[c].y * a[c].y;
        const int i = iiA[c];
#pragma unroll
        for (int w = 0; w < NQ; ++w) zp[w] += ((i >> (11 - w)) & 1) ? -pr : pr;
    }
#pragma unroll
    for (int w = 0; w < NQ; ++w) {
        float v = zp[w];
        for (int off = 32; off > 0; off >>= 1) v += __shfl_down(v, off, 64);
        zp[w] = v;
    }
    const int wave = tid >> 6;
    if (lane == 0) {
#pragma unroll
        for (int w = 0; w < NQ; ++w) zred[wave][w] = zp[w];
    }
    __syncthreads();
    if (tid < NQ) {
        float v = 0.0f;
#pragma unroll
        for (int k = 0; k < T / 64; ++k) v += zred[k][tid];
        zfin[tid] = v;
    }
    __syncthreads();

    // row[i] = b_up[i] + sum_j z[j] * w_up[i,j]
    if (tid < 784) {
        float acc = b_up[tid];
#pragma unroll
        for (int j = 0; j < NQ; ++j) acc += zfin[j] * w_up[tid * NQ + j];
        ((float*)row4)[tid] = acc;
    }
    __syncthreads();

    // broadcast: this block's 1024 float4 slots, k-strided (100352 = 196*512,
    // so idx%196 is invariant across k)
    const int idx = blockIdx.x * T + tid;          // 0..100351
    const float4 v = row4[idx % 196];
    float4* o = (float4*)out;
#pragma unroll
    for (int k = 0; k < 4; ++k) o[idx + k * 100352] = v;
}

extern "C" void kernel_launch(void* const* d_in, const int* in_sizes, int n_in,
                              void* d_out, int out_size, void* d_ws, size_t ws_size,
                              hipStream_t stream) {
    // inputs: 0:x 1:w_down 2:b_down 3:w_up 4:b_up 5:qweights
    const float* w_up = (const float*)d_in[3];
    const float* b_up = (const float*)d_in[4];
    const float* qw   = (const float*)d_in[5];
    float* out = (float*)d_out;

    qnn_fused<<<NBLK, T, 0, stream>>>(qw, w_up, b_up, out);
}

// Round 8
// 90.298 us; speedup vs baseline: 1.2912x; 1.0409x over previous
//
#include <hip/hip_runtime.h>

#define NQ     12
#define DIM    4096
#define QDEPTH 8
#define T      1024                    // 16 waves, 4 per SIMD
#define NBLK   98                      // 98*1024 threads * 4 float4 = 2048*784 floats

// involutive LDS swizzle: fold bits 9-6 into bits 3-0 -> even bank spread for
// both pass layouts (4 lanes/bank-pair, the wave64 x 8B floor).
__device__ __forceinline__ int SW(int i) { return i ^ ((i >> 6) & 0xF); }

// wave-internal xor exchanges, all barrier-free:
// KIND 0: xor1 (quad_perm)  1: xor2 (quad_perm)  2: xor4 (ds_swizzle BitMode)
// KIND 3: xor8 (row_ror:8 == lane^8 within a 16-lane row)
template <int KIND>
__device__ __forceinline__ float xlane(float x) {
    if constexpr (KIND == 0)
        return __int_as_float(__builtin_amdgcn_update_dpp(
            __float_as_int(x), __float_as_int(x), 0xB1, 0xF, 0xF, false));
    else if constexpr (KIND == 1)
        return __int_as_float(__builtin_amdgcn_update_dpp(
            __float_as_int(x), __float_as_int(x), 0x4E, 0xF, 0xF, false));
    else if constexpr (KIND == 2)
        return __int_as_float(__builtin_amdgcn_ds_swizzle(
            __float_as_int(x), 0x101F));   // xor lane^4
    else
        return __int_as_float(__builtin_amdgcn_update_dpp(
            __float_as_int(x), __float_as_int(x), 0x128, 0xF, 0xF, false));
}

// lane-bit gate: new = C.xy*own + C.zw*partner (C pre-selected per lane side)
template <int KIND>
__device__ __forceinline__ void lane_gate(float2 a[4], const float4 C) {
#pragma unroll
    for (int c = 0; c < 4; ++c) {
        const float pr = xlane<KIND>(a[c].x);
        const float pi = xlane<KIND>(a[c].y);
        const float ar = a[c].x, ai = a[c].y;
        a[c].x = C.x * ar - C.y * ai + C.z * pr - C.w * pi;
        a[c].y = C.x * ai + C.y * ar + C.z * pi + C.w * pr;
    }
}

// in-register gate on amp-index bit m: V0=(m00|m01), V1=(m11|m10)
__device__ __forceinline__ void reg_gate(float2 a[4], const int m,
                                         const float4 V0, const float4 V1) {
#pragma unroll
    for (int c = 0; c < 4; ++c) {
        if (c & m) continue;
        const int c1 = c | m;
        const float a0r = a[c].x,  a0i = a[c].y;
        const float a1r = a[c1].x, a1i = a[c1].y;
        a[c].x  = V0.x * a0r - V0.y * a0i + V0.z * a1r - V0.w * a1i;
        a[c].y  = V0.x * a0i + V0.y * a0r + V0.z * a1i + V0.w * a1r;
        a[c1].x = V1.z * a0r - V1.w * a0i + V1.x * a1r - V1.y * a1i;
        a[c1].y = V1.z * a0i + V1.w * a0r + V1.x * a1i + V1.y * a1r;
    }
}

// prefetch the 8 coefficient float4s for one 6-gate group into registers
__device__ __forceinline__ void load_coefs(const float4* __restrict__ m2,
                                           const int gi0, const int lane,
                                           float4 R[8]) {
    const float4* G = m2 + gi0 * 2;
    R[0] = G[0]; R[1] = G[1]; R[2] = G[2]; R[3] = G[3];
    R[4] = G[4  + ((lane >> 3) & 1)];
    R[5] = G[6  + ((lane >> 2) & 1)];
    R[6] = G[8  + ((lane >> 1) & 1)];
    R[7] = G[10 + ( lane       & 1)];
}

// 6 gates from preloaded registers (wire map: +0 -> c bit1, +1 -> c bit0,
// +2 -> lane bit3, +3 -> lane bit2, +4 -> lane bit1, +5 -> lane bit0)
__device__ __forceinline__ void apply6(float2 a[4], const float4 R[8]) {
    reg_gate(a, 2, R[0], R[1]);
    reg_gate(a, 1, R[2], R[3]);
    lane_gate<3>(a, R[4]);
    lane_gate<2>(a, R[5]);
    lane_gate<1>(a, R[6]);
    lane_gate<0>(a, R[7]);
}

// CZ-product diagonal for layer d (range r=d+1): sign = (-1)^popc(i & rotl12(i,r))
__device__ __forceinline__ void apply_cz(float2 a[4], const int ii[4], const int d) {
    const int r = d + 1;
#pragma unroll
    for (int c = 0; c < 4; ++c) {
        const unsigned i  = (unsigned)ii[c];
        const unsigned ro = ((i << r) | (i >> (12 - r))) & 0xFFFu;
        if (__popc(i & ro) & 1) { a[c].x = -a[c].x; a[c].y = -a[c].y; }
    }
}

// merged pass: coef prefetch -> barrier -> amp load -> gates(l1) -> CZ(d) ->
// gates(d+1) -> store
__device__ __forceinline__ void merged_pass(float2* __restrict__ st,
                                            const float4* __restrict__ m2,
                                            const int ja[4], const int ii[4],
                                            const int gbase, const int l1,
                                            const int d, const int lane,
                                            float2 a[4]) {
    float4 R1[8], R2[8];
    load_coefs(m2, l1 * NQ + gbase, lane, R1);   // pre-barrier: latency subsumed
    __syncthreads();
#pragma unroll
    for (int c = 0; c < 4; ++c) a[c] = st[ja[c]];
    load_coefs(m2, (d + 1) * NQ + gbase, lane, R2);  // hidden behind apply6(R1)
    apply6(a, R1);
    apply_cz(a, ii, d);
    apply6(a, R2);
#pragma unroll
    for (int c = 0; c < 4; ++c) st[ja[c]] = a[c];
}

// ---------------------------------------------------------------------------
// Fused kernel: every block redundantly simulates the 12-qubit circuit
// (batch-independent: the RZ input encoding on |0..0> is a global phase),
// computes the single output row, writes its 1/98th of the broadcast output.
// ---------------------------------------------------------------------------
__global__ __launch_bounds__(T) void qnn_fused(const float* __restrict__ qw,
                                               const float* __restrict__ w_up,
                                               const float* __restrict__ b_up,
                                               float* __restrict__ out) {
    __shared__ float2 st[DIM];
    __shared__ float4 mats2[96 * 2];   // per wire-gate: [m00|m01][m11|m10]
    __shared__ float  zred[T / 64][NQ];
    __shared__ float  zfin[NQ];
    __shared__ float4 row4[196];

    const int tid  = threadIdx.x;
    const int lane = tid & 63;

    if (tid < 96) {
        const float phi = qw[tid * 3 + 0], theta = qw[tid * 3 + 1], omega = qw[tid * 3 + 2];
        float c, s, sp, cp, sm, cm;
        sincosf(0.5f * theta, &s, &c);
        sincosf(0.5f * (phi + omega), &sp, &cp);
        sincosf(0.5f * (phi - omega), &sm, &cm);
        // Rot = RZ(omega) RY(theta) RZ(phi)
        mats2[tid * 2 + 0] = make_float4(cp * c, -sp * c, -cm * s, -sm * s); // m00|m01
        mats2[tid * 2 + 1] = make_float4(cp * c,  sp * c,  cm * s, -sm * s); // m11|m10
    }
    __syncthreads();

    // layout A: state bits 11-10 = c, 9-6 = lane bits 3-0, 5-4 = lane bits 5-4,
    //           3-0 = wave id.   (wires 0-5 in-thread)
    // layout B: state bits 11-10 = lane bits 5-4, 9-6 = wave id, 5-4 = c,
    //           3-0 = lane bits 3-0.   (wires 6-11 in-thread)
    const int w4 = (tid >> 6) & 0xF, l54 = (tid >> 4) & 3, l30 = tid & 0xF;
    int jaA[4], iiA[4], jaB[4], iiB[4];
#pragma unroll
    for (int c = 0; c < 4; ++c) {
        iiA[c] = (c << 10) | (l30 << 6) | (l54 << 4) | w4;
        iiB[c] = (l54 << 10) | (w4 << 6) | (c << 4) | l30;
        jaA[c] = SW(iiA[c]);
        jaB[c] = SW(iiB[c]);
    }

    float2 a[4];
    // ---- P1 (layout B): analytic init replaces the old P0 pass ----
    // After layer-0 wires 0-5 on |0..0>, amp[s] (bits5-0(s)==0) is the product
    // of first-column entries selected by bits 11-6 of s. Exact same complex-
    // mult sequence as the old gate pass -> bitwise identical.
    {
        float4 R1[8], R2[8];
        load_coefs(mats2, 0 * NQ + 6, lane, R1);
        load_coefs(mats2, 1 * NQ + 6, lane, R2);
        const int h = (l54 << 4) | w4;   // bits 11-6 of this thread's c=0 amp
        float pr = 1.f, pi = 0.f;
#pragma unroll
        for (int k = 0; k < 6; ++k) {
            const int b = (h >> (5 - k)) & 1;
            const float4 g0 = mats2[2 * k], g1 = mats2[2 * k + 1];
            const float cr = b ? g1.z : g0.x;   // m10 : m00
            const float ci = b ? g1.w : g0.y;
            const float nr = pr * cr - pi * ci;
            const float ni = pr * ci + pi * cr;
            pr = nr; pi = ni;
        }
        a[0] = (l30 == 0) ? make_float2(pr, pi) : make_float2(0.f, 0.f);
        a[1] = a[2] = a[3] = make_float2(0.f, 0.f);
        apply6(a, R1);            // layer 0, wires 6-11
        apply_cz(a, iiB, 0);      // CZ entangler, layer 0
        apply6(a, R2);            // layer 1, wires 6-11
#pragma unroll
        for (int c = 0; c < 4; ++c) st[jaB[c]] = a[c];
    }
    // ---- P2..P7: merged passes (7 barriers total incl. P8) ----
    merged_pass(st, mats2, jaA, iiA, 0, 1, 1, lane, a);   // L1 A, CZ1, L2 A
    merged_pass(st, mats2, jaB, iiB, 6, 2, 2, lane, a);   // L2 B, CZ2, L3 B
    merged_pass(st, mats2, jaA, iiA, 0, 3, 3, lane, a);   // L3 A, CZ3, L4 A
    merged_pass(st, mats2, jaB, iiB, 6, 4, 4, lane, a);   // L4 B, CZ4, L5 B
    merged_pass(st, mats2, jaA, iiA, 0, 5, 5, lane, a);   // L5 A, CZ5, L6 A
    merged_pass(st, mats2, jaB, iiB, 6, 6, 6, lane, a);   // L6 B, CZ6, L7 B
    // ---- P8 (layout A): layer 7 wires 0-5; layer-7 CZ diag dropped ----
    {
        float4 R1[8];
        load_coefs(mats2, 7 * NQ + 0, lane, R1);
        __syncthreads();
#pragma unroll
        for (int c = 0; c < 4; ++c) a[c] = st[jaA[c]];
        apply6(a, R1);
    }

    // <Z_w> reduction; final amp indices are iiA[c]
    float zp[NQ];
#pragma unroll
    for (int w = 0; w < NQ; ++w) zp[w] = 0.0f;
#pragma unroll
    for (int c = 0; c < 4; ++c) {
        const float pr = a[c].x * a[c].x + a[c].y * a[c].y;
        const int i = iiA[c];
#pragma unroll
        for (int w = 0; w < NQ; ++w) zp[w] += ((i >> (11 - w)) & 1) ? -pr : pr;
    }
#pragma unroll
    for (int w = 0; w < NQ; ++w) {
        float v = zp[w];
        for (int off = 32; off > 0; off >>= 1) v += __shfl_down(v, off, 64);
        zp[w] = v;
    }
    const int wave = tid >> 6;
    if (lane == 0) {
#pragma unroll
        for (int w = 0; w < NQ; ++w) zred[wave][w] = zp[w];
    }
    __syncthreads();
    if (tid < NQ) {
        float v = 0.0f;
#pragma unroll
        for (int k = 0; k < T / 64; ++k) v += zred[k][tid];
        zfin[tid] = v;
    }
    __syncthreads();

    // row[i] = b_up[i] + sum_j z[j] * w_up[i,j]
    if (tid < 784) {
        float acc = b_up[tid];
#pragma unroll
        for (int j = 0; j < NQ; ++j) acc += zfin[j] * w_up[tid * NQ + j];
        ((float*)row4)[tid] = acc;
    }
    __syncthreads();

    // broadcast: this block's 1024 float4 slots, k-strided (100352 = 196*512,
    // so idx%196 is invariant across k)
    const int idx = blockIdx.x * T + tid;          // 0..100351
    const float4 v = row4[idx % 196];
    float4* o = (float4*)out;
#pragma unroll
    for (int k = 0; k < 4; ++k) o[idx + k * 100352] = v;
}

extern "C" void kernel_launch(void* const* d_in, const int* in_sizes, int n_in,
                              void* d_out, int out_size, void* d_ws, size_t ws_size,
                              hipStream_t stream) {
    // inputs: 0:x 1:w_down 2:b_down 3:w_up 4:b_up 5:qweights
    const float* w_up = (const float*)d_in[3];
    const float* b_up = (const float*)d_in[4];
    const float* qw   = (const float*)d_in[5];
    float* out = (float*)d_out;

    qnn_fused<<<NBLK, T, 0, stream>>>(qw, w_up, b_up, out);
}